// Round 1
// baseline (290.547 us; speedup 1.0000x reference)
//
#include <hip/hip_runtime.h>

// KAN-CNN: out[b,f,h,w] = sum_{dy,dx,c} R_{f,dy,dx,c}( xpad[b,c,h+dy-1,w+dx-1] )
// R(x) = P5(x) / (1 + |x * Q(x)|), P5 Horner a0..a5, Q Horner b0..b3.
// Zero-padded taps contribute R(0) = a0 — handled by clamped-address load * 0 mult.

#define Bb 8
#define Cc 32
#define Hh 64
#define Ww 64
#define Ff 64
#define ROWS 4

__global__ __launch_bounds__(256) void kan_kernel(
    const float* __restrict__ x,     // [B,C,H,W]
    const float* __restrict__ ncf,   // [F,3,3,C,6]
    const float* __restrict__ dcf,   // [F,3,3,C,4]
    float* __restrict__ out)         // [B,F,H,W]
{
    const int t = threadIdx.x;
    const int w = t & 63;
    const int h = (int)blockIdx.y * ROWS + (t >> 6);
    const int f = (int)blockIdx.x;
    const int b = (int)blockIdx.z;

    // Precompute 9 tap offsets (clamped to valid memory) + 0/1 multipliers.
    int   offs[9];
    float mul[9];
#pragma unroll
    for (int dy = 0; dy < 3; ++dy) {
        const int hh = h + dy - 1;
        const bool vy = ((unsigned)hh < (unsigned)Hh);
#pragma unroll
        for (int dx = 0; dx < 3; ++dx) {
            const int ww = w + dx - 1;
            const bool v = vy && ((unsigned)ww < (unsigned)Ww);
            const int hc = v ? hh : h;
            const int wc = v ? ww : w;
            offs[dy * 3 + dx] = hc * Ww + wc;
            mul[dy * 3 + dx]  = v ? 1.0f : 0.0f;
        }
    }

    const float* __restrict__ xplane = x + (size_t)b * Cc * Hh * Ww;
    const float* __restrict__ nc = ncf + (size_t)f * 9 * Cc * 6;  // [(tap*C+c)*6 + j]
    const float* __restrict__ dc = dcf + (size_t)f * 9 * Cc * 4;  // [(tap*C+c)*4 + j]

    float acc = 0.0f;
    for (int c = 0; c < Cc; ++c) {
        const float* __restrict__ xp = xplane + c * Hh * Ww;
#pragma unroll
        for (int k2 = 0; k2 < 9; ++k2) {
            const float xv = xp[offs[k2]] * mul[k2];
            const float* __restrict__ a  = nc + (k2 * Cc + c) * 6; // block-uniform -> s_load
            const float* __restrict__ bd = dc + (k2 * Cc + c) * 4;
            float num = a[5];
            num = num * xv + a[4];
            num = num * xv + a[3];
            num = num * xv + a[2];
            num = num * xv + a[1];
            num = num * xv + a[0];
            float q = bd[3];
            q = q * xv + bd[2];
            q = q * xv + bd[1];
            q = q * xv + bd[0];
            const float den = 1.0f + __builtin_fabsf(q * xv);
            acc += num * __builtin_amdgcn_rcpf(den);
        }
    }

    out[(((size_t)b * Ff + f) * Hh + h) * Ww + w] = acc;
}

extern "C" void kernel_launch(void* const* d_in, const int* in_sizes, int n_in,
                              void* d_out, int out_size, void* d_ws, size_t ws_size,
                              hipStream_t stream) {
    const float* x   = (const float*)d_in[0];
    const float* ncf = (const float*)d_in[1];
    const float* dcf = (const float*)d_in[2];
    float* out = (float*)d_out;
    dim3 grid(Ff, Hh / ROWS, Bb);
    kan_kernel<<<grid, dim3(256), 0, stream>>>(x, ncf, dcf, out);
}

// Round 2
// 272.201 us; speedup vs baseline: 1.0674x; 1.0674x over previous
//
#include <hip/hip_runtime.h>

// KAN-CNN: out[b,f,h,w] = sum_{dy,dx,c} R_{f,dy,dx,c}( xpad[b,c,h+dy-1,w+dx-1] )
// R(x) = P5(x) / (1 + |x * Q(x)|), P5 Horner a0..a5, Q Horner b0..b3.
//
// R2 structure: pre-pad x into a zero-bordered [B,C,66,66] workspace so the
// hot kernel has NO boundary logic — all 9 tap addresses are one per-lane
// vaddr + compile-time constant instruction offsets (folds into the 13-bit
// signed `offset:` field; zero address VALU per tap). Zero-pad taps give
// R(0) = a0, exactly matching the reference's zero padding.

#define Bb 8
#define Cc 32
#define Hh 64
#define Ww 64
#define Ff 64
#define ROWS 4

#define PW 66                  // padded width/height
#define PPLANE (PW * PW)       // 4356 floats per padded plane
#define NPAD (Bb * Cc * PPLANE)

__global__ __launch_bounds__(256) void pad_kernel(
    const float* __restrict__ x,   // [B,C,64,64]
    float* __restrict__ xpad)      // [B,C,66,66]
{
    int idx = (int)blockIdx.x * 256 + (int)threadIdx.x;
    if (idx >= NPAD) return;
    int cell  = idx % PPLANE;
    int plane = idx / PPLANE;
    int hp = cell / PW;
    int wp = cell % PW;
    float v = 0.0f;
    if (hp >= 1 && hp <= Hh && wp >= 1 && wp <= Ww)
        v = x[(size_t)plane * (Hh * Ww) + (hp - 1) * Ww + (wp - 1)];
    xpad[idx] = v;
}

__global__ __launch_bounds__(256) void kan_kernel(
    const float* __restrict__ xpad,  // [B,C,66,66] zero-bordered
    const float* __restrict__ ncf,   // [F,3,3,C,6]
    const float* __restrict__ dcf,   // [F,3,3,C,4]
    float* __restrict__ out)         // [B,F,H,W]
{
    const int t = threadIdx.x;
    const int w = t & 63;
    const int h = (int)blockIdx.y * ROWS + (t >> 6);
    const int f = (int)blockIdx.x;
    const int b = (int)blockIdx.z;

    // Center address of this pixel in padded plane 0 of batch b.
    const float* __restrict__ xp0 =
        xpad + (size_t)b * Cc * PPLANE + (h + 1) * PW + (w + 1);

    const float* __restrict__ nc = ncf + (size_t)f * 9 * Cc * 6;
    const float* __restrict__ dc = dcf + (size_t)f * 9 * Cc * 4;

    // Compile-time tap offsets relative to center (padded row stride 66).
    // Unrolled -> folds into global_load_dword immediate offsets.
    float acc = 0.0f;
    for (int c = 0; c < Cc; ++c) {
        const float* __restrict__ xp = xp0 + c * PPLANE;
#pragma unroll
        for (int dy = 0; dy < 3; ++dy) {
#pragma unroll
            for (int dx = 0; dx < 3; ++dx) {
                const int k2 = dy * 3 + dx;
                const float xv = xp[(dy - 1) * PW + (dx - 1)];
                const float* __restrict__ a  = nc + (k2 * Cc + c) * 6;
                const float* __restrict__ bd = dc + (k2 * Cc + c) * 4;
                float num = a[5];
                num = num * xv + a[4];
                num = num * xv + a[3];
                num = num * xv + a[2];
                num = num * xv + a[1];
                num = num * xv + a[0];
                float q = bd[3];
                q = q * xv + bd[2];
                q = q * xv + bd[1];
                q = q * xv + bd[0];
                const float den = 1.0f + __builtin_fabsf(q * xv);
                acc += num * __builtin_amdgcn_rcpf(den);
            }
        }
    }

    out[(((size_t)b * Ff + f) * Hh + h) * Ww + w] = acc;
}

extern "C" void kernel_launch(void* const* d_in, const int* in_sizes, int n_in,
                              void* d_out, int out_size, void* d_ws, size_t ws_size,
                              hipStream_t stream) {
    const float* x   = (const float*)d_in[0];
    const float* ncf = (const float*)d_in[1];
    const float* dcf = (const float*)d_in[2];
    float* out  = (float*)d_out;
    float* xpad = (float*)d_ws;   // needs Bb*Cc*66*66*4 = 4.46 MB of ws

    pad_kernel<<<(NPAD + 255) / 256, 256, 0, stream>>>(x, xpad);

    dim3 grid(Ff, Hh / ROWS, Bb);
    kan_kernel<<<grid, dim3(256), 0, stream>>>(xpad, ncf, dcf, out);
}

// Round 3
// 219.869 us; speedup vs baseline: 1.3215x; 1.2380x over previous
//
#include <hip/hip_runtime.h>

// KAN-CNN: out[b,f,h,w] = sum_{dy,dx,c} R_{f,dy,dx,c}( xpad[b,c,h+dy-1,w+dx-1] )
// R(x) = P5(x)/(1+|x*Q(x)|), P5 Horner a0..a5, Q Horner b0..b3.
//
// R3 structure: issue-bound at the scalar-fp32 VALU roofline (R2: VALUBusy 97%,
// ~42-64 cyc/tap). Attack work-per-issue-slot: each thread computes a VERTICAL
// pixel pair (h0,h0+1) with <2 x float> ext_vector arithmetic so the 9 Horner
// steps lower to v_pk_fma_f32 (2 fp32 FMA per inst). Pair also shares x loads:
// 4 rows x 3 cols = 12 loads cover all 18 taps. Coefficients remain
// block-uniform sgpr scalars (VOP3P splat, 1-sgpr rule ok). abs/rcp scalar per
// half. Pre-padded [B,C,66,66] input (R2) keeps zero boundary logic.

typedef float v2f __attribute__((ext_vector_type(2)));

#define Bb 8
#define Cc 32
#define Hh 64
#define Ww 64
#define Ff 64

#define PW 66
#define PPLANE (PW * PW)
#define NPAD (Bb * Cc * PPLANE)
#define RPB 8   // rows per block = 4 rowpairs * 2

__global__ __launch_bounds__(256) void pad_kernel(
    const float* __restrict__ x,   // [B,C,64,64]
    float* __restrict__ xpad)      // [B,C,66,66]
{
    int idx = (int)blockIdx.x * 256 + (int)threadIdx.x;
    if (idx >= NPAD) return;
    int cell  = idx % PPLANE;
    int plane = idx / PPLANE;
    int hp = cell / PW;
    int wp = cell % PW;
    float v = 0.0f;
    if (hp >= 1 && hp <= Hh && wp >= 1 && wp <= Ww)
        v = x[(size_t)plane * (Hh * Ww) + (hp - 1) * Ww + (wp - 1)];
    xpad[idx] = v;
}

__global__ __launch_bounds__(256) void kan_kernel(
    const float* __restrict__ xpad,  // [B,C,66,66] zero-bordered
    const float* __restrict__ ncf,   // [F,3,3,C,6]
    const float* __restrict__ dcf,   // [F,3,3,C,4]
    float* __restrict__ out)         // [B,F,H,W]
{
    const int t  = threadIdx.x;
    const int w  = t & 63;
    const int rp = t >> 6;                       // rowpair 0..3
    const int h0 = (int)blockIdx.y * RPB + rp * 2;
    const int f  = (int)blockIdx.x;
    const int b  = (int)blockIdx.z;

    // padded address of pixel (h0, w)
    const float* __restrict__ xp =
        xpad + (size_t)b * Cc * PPLANE + (h0 + 1) * PW + (w + 1);

    const float* __restrict__ nc = ncf + (size_t)f * 9 * Cc * 6;
    const float* __restrict__ dc = dcf + (size_t)f * 9 * Cc * 4;

    v2f acc = {0.0f, 0.0f};

    for (int c = 0; c < Cc; ++c, xp += PPLANE) {
        // 4 rows x 3 cols cover the 18 taps of the vertical pixel pair.
        float r0[3], r1[3], r2[3], r3[3];
#pragma unroll
        for (int j = 0; j < 3; ++j) {
            r0[j] = xp[-PW + (j - 1)];
            r1[j] = xp[(j - 1)];
            r2[j] = xp[PW + (j - 1)];
            r3[j] = xp[2 * PW + (j - 1)];
        }
#pragma unroll
        for (int dy = 0; dy < 3; ++dy) {
#pragma unroll
            for (int dx = 0; dx < 3; ++dx) {
                const int k2 = dy * 3 + dx;
                v2f xv;
                xv.x = (dy == 0) ? r0[dx] : (dy == 1) ? r1[dx] : r2[dx];
                xv.y = (dy == 0) ? r1[dx] : (dy == 1) ? r2[dx] : r3[dx];

                const float* __restrict__ a  = nc + (k2 * Cc + c) * 6;
                const float* __restrict__ bd = dc + (k2 * Cc + c) * 4;

                v2f num = xv * a[5] + a[4];
                num = num * xv + a[3];
                num = num * xv + a[2];
                num = num * xv + a[1];
                num = num * xv + a[0];

                v2f q = xv * bd[3] + bd[2];
                q = q * xv + bd[1];
                q = q * xv + bd[0];

                v2f tt = q * xv;
                v2f r;
                r.x = __builtin_amdgcn_rcpf(1.0f + __builtin_fabsf(tt.x));
                r.y = __builtin_amdgcn_rcpf(1.0f + __builtin_fabsf(tt.y));
                acc += num * r;
            }
        }
    }

    const size_t o = (((size_t)b * Ff + f) * Hh + h0) * Ww + w;
    out[o]      = acc.x;
    out[o + Ww] = acc.y;
}

extern "C" void kernel_launch(void* const* d_in, const int* in_sizes, int n_in,
                              void* d_out, int out_size, void* d_ws, size_t ws_size,
                              hipStream_t stream) {
    const float* x   = (const float*)d_in[0];
    const float* ncf = (const float*)d_in[1];
    const float* dcf = (const float*)d_in[2];
    float* out  = (float*)d_out;
    float* xpad = (float*)d_ws;   // Bb*Cc*66*66*4 = 4.46 MB

    pad_kernel<<<(NPAD + 255) / 256, 256, 0, stream>>>(x, xpad);

    dim3 grid(Ff, Hh / RPB, Bb);
    kan_kernel<<<grid, dim3(256), 0, stream>>>(xpad, ncf, dcf, out);
}

// Round 4
// 216.580 us; speedup vs baseline: 1.3415x; 1.0152x over previous
//
#include <hip/hip_runtime.h>
#include <math.h>

// KAN-CNN: out[b,f,h,w] = sum_{dy,dx,c} R_{f,dy,dx,c}( xpad[b,c,h+dy-1,w+dx-1] )
// R(x) = P5(x)/(1+|x*Q(x)|), P5 Horner a0..a5, Q Horner b0..b3.
//
// R4: R3's <2 x float> arithmetic did NOT lower to v_pk_fma_f32 (issue-cycle
// arithmetic from counters matched the scalar ideal). Force it:
// __builtin_elementwise_fma on v2f -> llvm.fma.v2f32 -> v_pk_fma_f32 (packed
// fp32 is legal on gfx950; vector intrinsics can't be scalarized by SLP).
// Also: vertical QUAD per thread (two v2f chains, pixels h0..h0+3): 18 loads
// cover 36 taps, coefficient s_loads amortize over 4 pixels, and the two
// independent chains give ILP to hide SMEM/rcp latency. Grid = 2048 blocks =
// exactly 8 blocks/CU, full residency, no tail.

typedef float v2f __attribute__((ext_vector_type(2)));

#define Bb 8
#define Cc 32
#define Hh 64
#define Ww 64
#define Ff 64

#define PW 66
#define PPLANE (PW * PW)
#define NPAD (Bb * Cc * PPLANE)
#define RPB 16   // rows per block = 4 quads * 4

static __device__ __forceinline__ v2f sp(float s) { v2f v = {s, s}; return v; }

__global__ __launch_bounds__(256) void pad_kernel(
    const float* __restrict__ x,   // [B,C,64,64]
    float* __restrict__ xpad)      // [B,C,66,66]
{
    int idx = (int)blockIdx.x * 256 + (int)threadIdx.x;
    if (idx >= NPAD) return;
    int cell  = idx % PPLANE;
    int plane = idx / PPLANE;
    int hp = cell / PW;
    int wp = cell % PW;
    float v = 0.0f;
    if (hp >= 1 && hp <= Hh && wp >= 1 && wp <= Ww)
        v = x[(size_t)plane * (Hh * Ww) + (hp - 1) * Ww + (wp - 1)];
    xpad[idx] = v;
}

__global__ __launch_bounds__(256) void kan_kernel(
    const float* __restrict__ xpad,  // [B,C,66,66] zero-bordered
    const float* __restrict__ ncf,   // [F,3,3,C,6]
    const float* __restrict__ dcf,   // [F,3,3,C,4]
    float* __restrict__ out)         // [B,F,H,W]
{
    const int t  = threadIdx.x;
    const int w  = t & 63;
    const int qr = t >> 6;                        // quad index 0..3
    const int h0 = (int)blockIdx.y * RPB + qr * 4;
    const int f  = (int)blockIdx.x;
    const int b  = (int)blockIdx.z;

    // padded address of pixel (h0, w)'s center
    const float* __restrict__ xp =
        xpad + (size_t)b * Cc * PPLANE + (h0 + 1) * PW + (w + 1);

    const float* __restrict__ nc = ncf + (size_t)f * 9 * Cc * 6;
    const float* __restrict__ dc = dcf + (size_t)f * 9 * Cc * 4;

    v2f accA = {0.0f, 0.0f};   // pixels h0, h0+1
    v2f accB = {0.0f, 0.0f};   // pixels h0+2, h0+3

    for (int c = 0; c < Cc; ++c, xp += PPLANE) {
        // 6 rows x 3 cols cover the 36 taps of the vertical quad.
        float r[6][3];
#pragma unroll
        for (int j = 0; j < 6; ++j)
#pragma unroll
            for (int dx = 0; dx < 3; ++dx)
                r[j][dx] = xp[(j - 1) * PW + (dx - 1)];

#pragma unroll
        for (int dy = 0; dy < 3; ++dy) {
#pragma unroll
            for (int dx = 0; dx < 3; ++dx) {
                const int k2 = dy * 3 + dx;
                const float* __restrict__ a  = nc + (k2 * Cc + c) * 6;
                const float* __restrict__ bd = dc + (k2 * Cc + c) * 4;
                const float a0 = a[0], a1 = a[1], a2 = a[2];
                const float a3 = a[3], a4 = a[4], a5 = a[5];
                const float b0 = bd[0], b1 = bd[1], b2 = bd[2], b3 = bd[3];

                v2f xA = {r[dy][dx],     r[dy + 1][dx]};
                v2f xB = {r[dy + 2][dx], r[dy + 3][dx]};

                v2f nA = __builtin_elementwise_fma(xA, sp(a5), sp(a4));
                v2f nB = __builtin_elementwise_fma(xB, sp(a5), sp(a4));
                nA = __builtin_elementwise_fma(nA, xA, sp(a3));
                nB = __builtin_elementwise_fma(nB, xB, sp(a3));
                nA = __builtin_elementwise_fma(nA, xA, sp(a2));
                nB = __builtin_elementwise_fma(nB, xB, sp(a2));
                nA = __builtin_elementwise_fma(nA, xA, sp(a1));
                nB = __builtin_elementwise_fma(nB, xB, sp(a1));
                nA = __builtin_elementwise_fma(nA, xA, sp(a0));
                nB = __builtin_elementwise_fma(nB, xB, sp(a0));

                v2f qA = __builtin_elementwise_fma(xA, sp(b3), sp(b2));
                v2f qB = __builtin_elementwise_fma(xB, sp(b3), sp(b2));
                qA = __builtin_elementwise_fma(qA, xA, sp(b1));
                qB = __builtin_elementwise_fma(qB, xB, sp(b1));
                qA = __builtin_elementwise_fma(qA, xA, sp(b0));
                qB = __builtin_elementwise_fma(qB, xB, sp(b0));

                v2f tA = qA * xA;
                v2f tB = qB * xB;
                v2f rA, rB;
                rA.x = __builtin_amdgcn_rcpf(1.0f + __builtin_fabsf(tA.x));
                rA.y = __builtin_amdgcn_rcpf(1.0f + __builtin_fabsf(tA.y));
                rB.x = __builtin_amdgcn_rcpf(1.0f + __builtin_fabsf(tB.x));
                rB.y = __builtin_amdgcn_rcpf(1.0f + __builtin_fabsf(tB.y));

                accA = __builtin_elementwise_fma(nA, rA, accA);
                accB = __builtin_elementwise_fma(nB, rB, accB);
            }
        }
    }

    const size_t o = (((size_t)b * Ff + f) * Hh + h0) * Ww + w;
    out[o]          = accA.x;
    out[o + Ww]     = accA.y;
    out[o + 2 * Ww] = accB.x;
    out[o + 3 * Ww] = accB.y;
}

extern "C" void kernel_launch(void* const* d_in, const int* in_sizes, int n_in,
                              void* d_out, int out_size, void* d_ws, size_t ws_size,
                              hipStream_t stream) {
    const float* x   = (const float*)d_in[0];
    const float* ncf = (const float*)d_in[1];
    const float* dcf = (const float*)d_in[2];
    float* out  = (float*)d_out;
    float* xpad = (float*)d_ws;   // Bb*Cc*66*66*4 = 4.46 MB

    pad_kernel<<<(NPAD + 255) / 256, 256, 0, stream>>>(x, xpad);

    dim3 grid(Ff, Hh / RPB, Bb);
    kan_kernel<<<grid, dim3(256), 0, stream>>>(xpad, ncf, dcf, out);
}